// Round 17
// baseline (381.044 us; speedup 1.0000x reference)
//
#include <hip/hip_runtime.h>
#include <math.h>

#define EDIM 32
#define NG 64

typedef __attribute__((ext_vector_type(8))) _Float16 f16x8;
typedef __attribute__((ext_vector_type(4))) _Float16 f16x4;
typedef __attribute__((ext_vector_type(2))) _Float16 f16x2;
typedef __attribute__((ext_vector_type(4))) float f32x4;

#if __has_builtin(__builtin_amdgcn_fdot2)
#define USE_FDOT2 1
#else
#define USE_FDOT2 0
#endif

#define THR 4.0f

__device__ inline unsigned enc_f(float f){
  unsigned b = __float_as_uint(f);
  return (b & 0x80000000u) ? ~b : (b | 0x80000000u);
}
__device__ inline float dec_f(unsigned u){
  unsigned b = (u & 0x80000000u) ? (u & 0x7FFFFFFFu) : ~u;
  return __uint_as_float(b);
}
__device__ inline float redux16(float v){
  #pragma unroll
  for (int off=1; off<16; off<<=1) v += __shfl_xor(v, off, 64);
  return v;
}
__device__ inline f16x8 bcast8(_Float16 h){
  f16x8 r;
  #pragma unroll
  for (int z=0;z<8;z++) r[z]=h;
  return r;
}
__device__ inline f16x8 shfl_xor_f16x8(f16x8 v, int off){
  union { f16x8 h; int i[4]; } u;
  u.h = v;
  #pragma unroll
  for (int z=0;z<4;z++) u.i[z] = __shfl_xor(u.i[z], off, 64);
  return u.h;
}
// leaky-relu(m) . att  over 8 f16 channels
__device__ inline float dot_leaky(f16x8 m8, f16x8 a8){
#if __has_builtin(__builtin_elementwise_max)
  f16x8 lm = __builtin_elementwise_max(m8, m8*(_Float16)0.2f);
#else
  f16x8 lm;
  #pragma unroll
  for (int z=0;z<8;z++){ _Float16 v=m8[z]; lm[z] = (v>(_Float16)0)? v : v*(_Float16)0.2f; }
#endif
  float s = 0.f;
#if USE_FDOT2
  #pragma unroll
  for (int z=0;z<4;z++){
    f16x2 u; u[0]=lm[2*z]; u[1]=lm[2*z+1];
    f16x2 w2; w2[0]=a8[2*z]; w2[1]=a8[2*z+1];
    s = __builtin_amdgcn_fdot2(u, w2, s, false);
  }
#else
  #pragma unroll
  for (int z=0;z<8;z++) s += (float)lm[z]*(float)a8[z];
#endif
  return s;
}

// ---------- fused setup: rel tables + weight transposes + bias/att concat ----------
__global__ __launch_bounds__(256) void k_setup(
    const float* __restrict__ emb, const float* __restrict__ irf,
    const float* __restrict__ We1, const float* __restrict__ We2,
    const float* __restrict__ Wl1, const float* __restrict__ Wr1, const float* __restrict__ skipW,
    const float* __restrict__ Wl2, const float* __restrict__ Wr2,
    const float* __restrict__ bl1, const float* __restrict__ br1, const float* __restrict__ skipb,
    const float* __restrict__ bl2, const float* __restrict__ br2,
    const float* __restrict__ att1, const float* __restrict__ att2,
    _Float16* __restrict__ efb1h, _Float16* __restrict__ efb2h,
    _Float16* __restrict__ W1cat, _Float16* __restrict__ W2cat,
    float* __restrict__ bcat1, float* __restrict__ bcat2,
    _Float16* __restrict__ att1h, _Float16* __restrict__ att2h)
{
  int b = blockIdx.x, t = threadIdx.x;
  if (b < 40){
    __shared__ float bb[EDIM];
    int r = b;
    if (t < 32){
      float v = emb[r*EDIM + t];
      float ss = v*v;
      #pragma unroll
      for (int off=16; off>0; off>>=1) ss += __shfl_xor(ss, off, 64);
      float nrm = sqrtf(ss);
      float w = v / fmaxf(nrm, 1e-12f) * irf[r];
      bb[t] = w;
    }
    __syncthreads();
    float a1 = 0.f;
    #pragma unroll
    for (int k=0;k<EDIM;k++) a1 += bb[k]*We1[k*256 + t];
    efb1h[r*256 + t] = (_Float16)a1;
    if (t < 128){
      float a2 = 0.f;
      #pragma unroll
      for (int k=0;k<EDIM;k++) a2 += bb[k]*We2[k*128 + t];
      efb2h[r*128 + t] = (_Float16)a2;
    }
  }
  else if (b < 296){ int idx=(b-40)*256+t;  int k=idx>>8, n2=idx&255; W1cat[n2*256+k]          = (_Float16)Wl1[idx]; }
  else if (b < 552){ int idx=(b-296)*256+t; int k=idx>>8, n2=idx&255; W1cat[65536+n2*256+k]    = (_Float16)Wr1[idx]; }
  else if (b < 680){ int idx=(b-552)*256+t; int k=idx>>7, n2=idx&127; W1cat[131072+n2*256+k]   = (_Float16)skipW[idx]; }
  else if (b < 744){ int idx=(b-680)*256+t; int k=idx>>7, n2=idx&127; W2cat[n2*128+k]          = (_Float16)Wl2[idx]; }
  else if (b < 808){ int idx=(b-744)*256+t; int k=idx>>7, n2=idx&127; W2cat[16384+n2*128+k]    = (_Float16)Wr2[idx]; }
  else if (b == 808){ bcat1[t] = bl1[t]; }
  else if (b == 809){
    bcat1[256+t] = br1[t];
    if (t < 128) bcat1[512+t] = skipb[t];
    att1h[t] = (_Float16)att1[t];
  } else {
    if (t < 128){
      bcat2[t] = bl2[t];
      bcat2[128+t] = br2[t];
      att2h[t] = (_Float16)att2[t];
    }
  }
}

// ---------- x -> fp16 ----------
__global__ void k_xcvt(const float* __restrict__ x, _Float16* __restrict__ xh, int total8){
  int i = blockIdx.x*256 + threadIdx.x;
  if (i < total8){
    float4 v0 = *(const float4*)&x[(size_t)i*8];
    float4 v1 = *(const float4*)&x[(size_t)i*8 + 4];
    f16x8 o;
    o[0]=(_Float16)v0.x; o[1]=(_Float16)v0.y; o[2]=(_Float16)v0.z; o[3]=(_Float16)v0.w;
    o[4]=(_Float16)v1.x; o[5]=(_Float16)v1.y; o[6]=(_Float16)v1.z; o[7]=(_Float16)v1.w;
    *(f16x8*)&xh[(size_t)i*8] = o;
  }
}

// ---------- CSR build ----------
__global__ void k_count(const int* __restrict__ dst, int* __restrict__ cnt, int E){
  int e = blockIdx.x*256 + threadIdx.x;
  if (e < E) atomicAdd(&cnt[dst[e]], 1);
}

__global__ __launch_bounds__(1024) void k_scan1(const int* __restrict__ cnt, int* __restrict__ incl,
                                                int* __restrict__ bsum, int n){
  __shared__ int s[1024];
  int i = blockIdx.x*1024 + threadIdx.x;
  int v = (i<n)? cnt[i] : 0;
  s[threadIdx.x] = v; __syncthreads();
  for (int off=1; off<1024; off<<=1){
    int add = (threadIdx.x>=(unsigned)off)? s[threadIdx.x-off] : 0;
    __syncthreads();
    s[threadIdx.x] += add;
    __syncthreads();
  }
  if (i<n) incl[i] = s[threadIdx.x];
  if (threadIdx.x==1023) bsum[blockIdx.x] = s[1023];
}
__global__ void k_scan2(int* __restrict__ bsum, int nb){
  if (threadIdx.x==0 && blockIdx.x==0){
    int acc=0;
    for (int b=0;b<nb;b++){ int t=bsum[b]; bsum[b]=acc; acc+=t; }
  }
}
__global__ void k_scan3(const int* __restrict__ incl, const int* __restrict__ bsum,
                        int* __restrict__ rowptr, int n){
  int i = blockIdx.x*256 + threadIdx.x;
  if (i<n) rowptr[i+1] = incl[i] + bsum[i>>10];
  if (i==0) rowptr[0] = 0;
}
// scatter ONE packed 8B record per edge: {src | rel<<20, w-bits}
__global__ void k_fill(const int* __restrict__ src, const int* __restrict__ dst,
                       const int* __restrict__ rel, const float* __restrict__ ew,
                       const int* __restrict__ rowptr, int* __restrict__ fill,
                       int2* __restrict__ epack, int E){
  int e = blockIdx.x*256 + threadIdx.x;
  if (e<E){
    int d = dst[e];
    int pos = rowptr[d] + atomicAdd(&fill[d],1);
    int2 rec;
    rec.x = src[e] | (rel[e]<<20);
    rec.y = __float_as_int(ew[e]);
    epack[pos] = rec;
  }
}

// ---------- fp16 MFMA GEMM (double-buffered, XCD-chunk-swizzled, split C output) ----------
// cols < split -> C1 (ld1), cols >= split -> C2 (ld2)
__global__ __launch_bounds__(256) void k_gemm_f16(
    const _Float16* __restrict__ A, const _Float16* __restrict__ Bt,
    const float* __restrict__ bias,
    _Float16* __restrict__ C1, int ld1,
    _Float16* __restrict__ C2, int ld2, int split,
    int M, int N, int K)
{
  __shared__ __attribute__((aligned(16))) _Float16 As[2][128][40];
  __shared__ __attribute__((aligned(16))) _Float16 Bs[2][128][40];
  int tid = threadIdx.x;
  int wid = tid>>6, lane = tid&63;
  int wm = (wid>>1)*64, wn = (wid&1)*64;
  int nwg = gridDim.x*gridDim.y;
  int d = blockIdx.y*gridDim.x + blockIdx.x;
  int q = nwg>>3, r = nwg&7;
  int xcd = d & 7, idx = d >> 3;
  int logical = xcd*q + min(xcd, r) + idx;
  int bx = logical % gridDim.x, by = logical / gridDim.x;
  int bm = by*128, bn = bx*128;
  int frow = lane&15, fk = (lane>>4)*8;
  int r0c = tid>>2,        s0c = (tid&3)*8;
  int r1c = (tid+256)>>2,  s1c = (tid&3)*8;
  auto loadA = [&](int rr, int s, int k0)->f16x8{
    int gr = bm + rr;
    f16x8 v;
    if (gr < M) v = *(const f16x8*)&A[(size_t)gr*K + k0 + s];
    else { for (int z=0;z<8;z++) v[z]=(_Float16)0.f; }
    return v;
  };
  auto loadB = [&](int rr, int s, int k0)->f16x8{
    return *(const f16x8*)&Bt[(size_t)(bn+rr)*K + k0 + s];
  };
  f32x4 acc[4][4] = {};
  int nt = K >> 5;
  {
    f16x8 a0 = loadA(r0c,s0c,0), a1 = loadA(r1c,s1c,0);
    f16x8 b0 = loadB(r0c,s0c,0), b1 = loadB(r1c,s1c,0);
    *(f16x8*)&As[0][r0c][s0c] = a0;  *(f16x8*)&As[0][r1c][s1c] = a1;
    *(f16x8*)&Bs[0][r0c][s0c] = b0;  *(f16x8*)&Bs[0][r1c][s1c] = b1;
  }
  for (int t=0; t<nt; t++){
    int cur = t&1, nxt = cur^1;
    __syncthreads();
    f16x8 a0,a1,b0,b1;
    bool pf = (t+1 < nt);
    if (pf){
      int k0 = (t+1)<<5;
      a0 = loadA(r0c,s0c,k0); a1 = loadA(r1c,s1c,k0);
      b0 = loadB(r0c,s0c,k0); b1 = loadB(r1c,s1c,k0);
    }
    f16x8 af[4], bfr[4];
    #pragma unroll
    for (int i=0;i<4;i++) af[i]  = *(f16x8*)&As[cur][wm + i*16 + frow][fk];
    #pragma unroll
    for (int j=0;j<4;j++) bfr[j] = *(f16x8*)&Bs[cur][wn + j*16 + frow][fk];
    #pragma unroll
    for (int i=0;i<4;i++)
      #pragma unroll
      for (int j=0;j<4;j++)
        acc[i][j] = __builtin_amdgcn_mfma_f32_16x16x32_f16(af[i], bfr[j], acc[i][j], 0,0,0);
    if (pf){
      *(f16x8*)&As[nxt][r0c][s0c] = a0;  *(f16x8*)&As[nxt][r1c][s1c] = a1;
      *(f16x8*)&Bs[nxt][r0c][s0c] = b0;  *(f16x8*)&Bs[nxt][r1c][s1c] = b1;
    }
  }
  int cl = lane&15, rq = (lane>>4)*4;
  #pragma unroll
  for (int i=0;i<4;i++){
    #pragma unroll
    for (int r4=0;r4<4;r4++){
      int gr = bm + wm + i*16 + rq + r4;
      if (gr < M){
        #pragma unroll
        for (int j=0;j<4;j++){
          int gc = bn + wn + j*16 + cl;
          _Float16 v = (_Float16)(acc[i][j][r4] + bias[gc]);
          if (gc < split) C1[(size_t)gr*ld1 + gc] = v;
          else            C2[(size_t)gr*ld2 + (gc-split)] = v;
        }
      }
    }
  }
}

// ---------- fused GATv2 layer 1: H=2; fused efs; compact gather table xl1h[N][256] ----------
__global__ __launch_bounds__(256) void k_attn1(
  const _Float16* __restrict__ xl1h, const _Float16* __restrict__ xrsk,
  const _Float16* __restrict__ efb1h, const _Float16* __restrict__ att1h,
  const float* __restrict__ bias1, const int* __restrict__ rowptr,
  const int2* __restrict__ epack,
  _Float16* __restrict__ h1, int N)
{
  int wv = threadIdx.x>>6, lane = threadIdx.x&63;
  int n = blockIdx.x*4 + wv;
  if (n >= N) return;
  int sub = (lane>>4)&1, t16 = lane&15;
  int ch = (lane>>5)*128 + t16*8;
  f16x8 xrh = *(const f16x8*)&xrsk[(size_t)n*384 + ch];
  f16x8 xlh = *(const f16x8*)&xl1h[((size_t)n<<8) + ch];
  f16x8 ath = *(const f16x8*)&att1h[ch];
  f16x8 acc_h = bcast8((_Float16)0.f);
  f16x8 efs_h = bcast8((_Float16)0.f);
  float mx = -1e30f, den = 0.f;

  int beg=rowptr[n], end=rowptr[n+1], p=beg;
  for (; p+4<=end; p+=4){
    int2 pA = epack[p+sub], pB = epack[p+2+sub];
    int iA = (pA.x & 0xFFFFF)<<8, rA = (pA.x>>20)<<8; float wA = __int_as_float(pA.y);
    int iB = (pB.x & 0xFFFFF)<<8, rB = (pB.x>>20)<<8; float wB = __int_as_float(pB.y);
    f16x8 xvA = *(const f16x8*)&xl1h[(size_t)iA + ch];
    f16x8 eeA = *(const f16x8*)&efb1h[rA + ch];
    f16x8 xvB = *(const f16x8*)&xl1h[(size_t)iB + ch];
    f16x8 eeB = *(const f16x8*)&efb1h[rB + ch];
    f16x8 wA8 = bcast8((_Float16)wA), wB8 = bcast8((_Float16)wB);
    f16x8 tA = wA8*eeA, tB = wB8*eeB;
    efs_h = efs_h + tA + tB;
    f16x8 mA = xvA + xrh + tA;
    f16x8 mB = xvB + xrh + tB;
    float sA = dot_leaky(mA, ath);
    float sB = dot_leaky(mB, ath);
    #pragma unroll
    for (int off=1; off<16; off<<=1){
      sA += __shfl_xor(sA, off, 64);
      sB += __shfl_xor(sB, off, 64);
    }
    float gmax = fmaxf(sA, sB);
    if (__all(gmax <= mx + THR)){
      float gA = __expf(sA-mx), gB = __expf(sB-mx);
      den += gA + gB;
      f16x8 gA8 = bcast8((_Float16)gA), gB8 = bcast8((_Float16)gB);
      acc_h = acc_h + xvA*gA8 + xvB*gB8;
    } else {
      float nm = fmaxf(mx, gmax);
      float f = __expf(mx-nm), gA = __expf(sA-nm), gB = __expf(sB-nm);
      den = den*f + gA + gB;
      f16x8 f8 = bcast8((_Float16)f), gA8 = bcast8((_Float16)gA), gB8 = bcast8((_Float16)gB);
      acc_h = acc_h*f8 + xvA*gA8 + xvB*gB8;
      mx = nm;
    }
  }
  for (; p+2<=end; p+=2){
    int2 pE = epack[p+sub];
    int i0 = (pE.x & 0xFFFFF)<<8, r0 = (pE.x>>20)<<8; float w0 = __int_as_float(pE.y);
    f16x8 xv = *(const f16x8*)&xl1h[(size_t)i0 + ch];
    f16x8 ee = *(const f16x8*)&efb1h[r0 + ch];
    f16x8 w8 = bcast8((_Float16)w0);
    f16x8 t0 = w8*ee;
    efs_h = efs_h + t0;
    f16x8 m8 = xv + xrh + t0;
    float sc = redux16(dot_leaky(m8, ath));
    float nm = fmaxf(mx, sc);
    float f = __expf(mx-nm), ge = __expf(sc-nm);
    den = den*f + ge;
    f16x8 f8 = bcast8((_Float16)f), g8 = bcast8((_Float16)ge);
    acc_h = acc_h*f8 + xv*g8;
    mx = nm;
  }
  if (p < end && sub == 0){
    int2 pE = epack[p];
    int i0 = (pE.x & 0xFFFFF)<<8, r0 = (pE.x>>20)<<8; float w0 = __int_as_float(pE.y);
    f16x8 xv = *(const f16x8*)&xl1h[(size_t)i0 + ch];
    f16x8 ee = *(const f16x8*)&efb1h[r0 + ch];
    f16x8 w8 = bcast8((_Float16)w0);
    f16x8 t0 = w8*ee;
    efs_h = efs_h + t0;
    f16x8 m8 = xv + xrh + t0;
    float sc = redux16(dot_leaky(m8, ath));
    float nm = fmaxf(mx, sc);
    float f = __expf(mx-nm), ge = __expf(sc-nm);
    den = den*f + ge;
    f16x8 f8 = bcast8((_Float16)f), g8 = bcast8((_Float16)ge);
    acc_h = acc_h*f8 + xv*g8;
    mx = nm;
  }
  float acc[8];
  #pragma unroll
  for (int z=0;z<8;z++) acc[z] = (float)acc_h[z];
  // merge the two edge-parity groups within each head (acc, den, mx, efs)
  {
    float mo = __shfl_xor(mx, 16, 64);
    float dn = __shfl_xor(den, 16, 64);
    float ao[8];
    #pragma unroll
    for (int z=0;z<8;z++) ao[z] = __shfl_xor(acc[z], 16, 64);
    float mt = fmaxf(mx, mo);
    float fs = __expf(mx-mt), fo = __expf(mo-mt);
    den = den*fs + dn*fo;
    #pragma unroll
    for (int z=0;z<8;z++) acc[z] = acc[z]*fs + ao[z]*fo;
    mx = mt;
    efs_h = efs_h + shfl_xor_f16x8(efs_h, 16);
  }
  // self-loop term (fused efs/deg), merged last
  {
    float invdeg = 1.f / (float)max(end-beg, 1);
    f16x8 efh;
    #pragma unroll
    for (int z=0;z<8;z++) efh[z] = (_Float16)((float)efs_h[z]*invdeg);
    f16x8 mself = xlh + xrh + efh;
    float s = redux16(dot_leaky(mself, ath));
    float nm = fmaxf(mx, s);
    float f = __expf(mx-nm), gs = __expf(s-nm);
    den = den*f + gs;
    #pragma unroll
    for (int z=0;z<8;z++) acc[z] = acc[z]*f + gs*(float)xlh[z];
    mx = nm;
  }
  float inv = 1.f/(den + 1e-16f);
  float res[8];
  #pragma unroll
  for (int z=0;z<8;z++){
    float v = acc[z]*inv;
    float o = __shfl_xor(v, 32, 64);
    res[z] = 0.5f*(v + o);
  }
  if (lane < 16){
    f16x8 skh = *(const f16x8*)&xrsk[(size_t)n*384 + 256 + t16*8];
    f32x4 b0 = *(const f32x4*)&bias1[t16*8];
    f32x4 b1 = *(const f32x4*)&bias1[t16*8 + 4];
    f16x8 o;
    #pragma unroll
    for (int z=0;z<4;z++) o[z]   = (_Float16)fmaxf(res[z]   + b0[z] + (float)skh[z],   0.f);
    #pragma unroll
    for (int z=0;z<4;z++) o[4+z] = (_Float16)fmaxf(res[4+z] + b1[z] + (float)skh[4+z], 0.f);
    *(f16x8*)&h1[(size_t)n*128 + t16*8] = o;
  }
}

// ---------- fused GATv2 layer 2: H=1; fused efs; compact gather table xl2h[N][128] ----------
__global__ __launch_bounds__(256) void k_attn2(
  const _Float16* __restrict__ xl2h, const _Float16* __restrict__ xr2h,
  const _Float16* __restrict__ efb2h, const _Float16* __restrict__ att2h,
  const float* __restrict__ bias2, const int* __restrict__ rowptr,
  const int2* __restrict__ epack,
  float* __restrict__ h2, int N)
{
  int wv = threadIdx.x>>6, lane = threadIdx.x&63;
  int n = blockIdx.x*4 + wv;
  if (n >= N) return;
  int g = lane>>4, t16 = lane&15;
  int ch = t16*8;
  f16x8 xrh = *(const f16x8*)&xr2h[((size_t)n<<7) + ch];
  f16x8 xlh = *(const f16x8*)&xl2h[((size_t)n<<7) + ch];
  f16x8 ath = *(const f16x8*)&att2h[ch];
  f16x8 acc_h = bcast8((_Float16)0.f);
  f16x8 efs_h = bcast8((_Float16)0.f);
  float mx = -1e30f, den = 0.f;

  int beg=rowptr[n], end=rowptr[n+1], p=beg;
  for (; p+8<=end; p+=8){
    int2 pA = epack[p+g], pB = epack[p+4+g];
    int iA = (pA.x & 0xFFFFF)<<7, rA = (pA.x>>20)<<7; float wA = __int_as_float(pA.y);
    int iB = (pB.x & 0xFFFFF)<<7, rB = (pB.x>>20)<<7; float wB = __int_as_float(pB.y);
    f16x8 xvA = *(const f16x8*)&xl2h[(size_t)iA + ch];
    f16x8 eeA = *(const f16x8*)&efb2h[rA + ch];
    f16x8 xvB = *(const f16x8*)&xl2h[(size_t)iB + ch];
    f16x8 eeB = *(const f16x8*)&efb2h[rB + ch];
    f16x8 wA8 = bcast8((_Float16)wA), wB8 = bcast8((_Float16)wB);
    f16x8 tA = wA8*eeA, tB = wB8*eeB;
    efs_h = efs_h + tA + tB;
    f16x8 mA = xvA + xrh + tA;
    f16x8 mB = xvB + xrh + tB;
    float sA = dot_leaky(mA, ath);
    float sB = dot_leaky(mB, ath);
    #pragma unroll
    for (int off=1; off<16; off<<=1){
      sA += __shfl_xor(sA, off, 64);
      sB += __shfl_xor(sB, off, 64);
    }
    float gmax = fmaxf(sA, sB);
    if (__all(gmax <= mx + THR)){
      float gA = __expf(sA-mx), gB = __expf(sB-mx);
      den += gA + gB;
      f16x8 gA8 = bcast8((_Float16)gA), gB8 = bcast8((_Float16)gB);
      acc_h = acc_h + xvA*gA8 + xvB*gB8;
    } else {
      float nm = fmaxf(mx, gmax);
      float f = __expf(mx-nm), gA = __expf(sA-nm), gB = __expf(sB-nm);
      den = den*f + gA + gB;
      f16x8 f8 = bcast8((_Float16)f), gA8 = bcast8((_Float16)gA), gB8 = bcast8((_Float16)gB);
      acc_h = acc_h*f8 + xvA*gA8 + xvB*gB8;
      mx = nm;
    }
  }
  for (; p+4<=end; p+=4){
    int2 pE = epack[p+g];
    int i0 = (pE.x & 0xFFFFF)<<7, r0 = (pE.x>>20)<<7; float w0 = __int_as_float(pE.y);
    f16x8 xv = *(const f16x8*)&xl2h[(size_t)i0 + ch];
    f16x8 ee = *(const f16x8*)&efb2h[r0 + ch];
    f16x8 w8 = bcast8((_Float16)w0);
    f16x8 t0 = w8*ee;
    efs_h = efs_h + t0;
    f16x8 m8 = xv + xrh + t0;
    float sc = redux16(dot_leaky(m8, ath));
    float nm = fmaxf(mx, sc);
    float f = __expf(mx-nm), ge = __expf(sc-nm);
    den = den*f + ge;
    f16x8 f8 = bcast8((_Float16)f), g8 = bcast8((_Float16)ge);
    acc_h = acc_h*f8 + xv*g8;
    mx = nm;
  }
  int rem = end - p;
  if (g < rem){
    int2 pE = epack[p+g];
    int i0 = (pE.x & 0xFFFFF)<<7, r0 = (pE.x>>20)<<7; float w0 = __int_as_float(pE.y);
    f16x8 xv = *(const f16x8*)&xl2h[(size_t)i0 + ch];
    f16x8 ee = *(const f16x8*)&efb2h[r0 + ch];
    f16x8 w8 = bcast8((_Float16)w0);
    f16x8 t0 = w8*ee;
    efs_h = efs_h + t0;
    f16x8 m8 = xv + xrh + t0;
    float sc = redux16(dot_leaky(m8, ath));
    float nm = fmaxf(mx, sc);
    float f = __expf(mx-nm), ge = __expf(sc-nm);
    den = den*f + ge;
    f16x8 f8 = bcast8((_Float16)f), g8 = bcast8((_Float16)ge);
    acc_h = acc_h*f8 + xv*g8;
    mx = nm;
  }
  float acc[8];
  #pragma unroll
  for (int z=0;z<8;z++) acc[z] = (float)acc_h[z];
  // butterfly-merge the 4 group states (acc, den, mx, efs)
  #pragma unroll
  for (int off=16; off<=32; off<<=1){
    float mo = __shfl_xor(mx, off, 64);
    float dn = __shfl_xor(den, off, 64);
    float ao[8];
    #pragma unroll
    for (int z=0;z<8;z++) ao[z] = __shfl_xor(acc[z], off, 64);
    float mt = fmaxf(mx, mo);
    float fs = __expf(mx-mt), fo = __expf(mo-mt);
    den = den*fs + dn*fo;
    #pragma unroll
    for (int z=0;z<8;z++) acc[z] = acc[z]*fs + ao[z]*fo;
    mx = mt;
    efs_h = efs_h + shfl_xor_f16x8(efs_h, off);
  }
  // self-loop term
  {
    float invdeg = 1.f / (float)max(end-beg, 1);
    f16x8 efh;
    #pragma unroll
    for (int z=0;z<8;z++) efh[z] = (_Float16)((float)efs_h[z]*invdeg);
    f16x8 mself = xlh + xrh + efh;
    float s = redux16(dot_leaky(mself, ath));
    float nm = fmaxf(mx, s);
    float f = __expf(mx-nm), gs = __expf(s-nm);
    den = den*f + gs;
    #pragma unroll
    for (int z=0;z<8;z++) acc[z] = acc[z]*f + gs*(float)xlh[z];
    mx = nm;
  }
  float inv = 1.f/(den + 1e-16f);
  if (g == 0){
    f32x4 b0 = *(const f32x4*)&bias2[ch];
    f32x4 b1 = *(const f32x4*)&bias2[ch+4];
    f32x4 o0, o1;
    #pragma unroll
    for (int z=0;z<4;z++){ o0[z] = fmaxf(acc[z]*inv   + b0[z], 0.f);
                           o1[z] = fmaxf(acc[4+z]*inv + b1[z], 0.f); }
    *(f32x4*)&h2[(size_t)n*128 + ch]     = o0;
    *(f32x4*)&h2[(size_t)n*128 + ch + 4] = o1;
  }
}

// ---------- graph boundaries ----------
__global__ void k_start(const int* __restrict__ batch, int* __restrict__ start, int N){
  int i = blockIdx.x*256 + threadIdx.x;
  if (i >= N) return;
  int b = batch[i];
  int pb = (i==0)? -1 : batch[i-1];
  for (int g=pb+1; g<=b; g++) start[g] = i;
  if (i == N-1){ for (int g=b+1; g<=NG; g++) start[g] = N; }
}

// ---------- pooling stage A (x read as fp16 xh) ----------
#define PCHUNK 32
__global__ __launch_bounds__(256) void k_pool_part(const _Float16* __restrict__ xh, const _Float16* __restrict__ h1,
                       const float* __restrict__ h2, const int* __restrict__ batch,
                       unsigned* __restrict__ umax, float* __restrict__ fsum, int N){
  int c0 = blockIdx.x * PCHUNK;
  int c1 = min(c0 + PCHUNK, N);
  if (c0 >= N) return;
  int t = threadIdx.x;
  float mx0 = -INFINITY, sm0 = 0.f, mx1 = -INFINITY, sm1 = 0.f;
  int bcur = batch[c0];
  for (int i=c0;i<c1;i++){
    int b = batch[i];
    if (b != bcur){
      atomicMax(&umax[bcur*512 + t], enc_f(mx0));
      atomicAdd(&fsum[bcur*512 + t], sm0);
      atomicMax(&umax[bcur*512 + 256 + t], enc_f(mx1));
      atomicAdd(&fsum[bcur*512 + 256 + t], sm1);
      mx0 = mx1 = -INFINITY; sm0 = sm1 = 0.f; bcur = b;
    }
    float v0 = (float)xh[(size_t)i*256 + t];
    float v1 = (t<128) ? (float)h1[(size_t)i*128 + t] : h2[(size_t)i*128 + (t-128)];
    mx0 = fmaxf(mx0, v0); sm0 += v0;
    mx1 = fmaxf(mx1, v1); sm1 += v1;
  }
  atomicMax(&umax[bcur*512 + t], enc_f(mx0));
  atomicAdd(&fsum[bcur*512 + t], sm0);
  atomicMax(&umax[bcur*512 + 256 + t], enc_f(mx1));
  atomicAdd(&fsum[bcur*512 + 256 + t], sm1);
}

// ---------- pooling stage B ----------
__global__ void k_pool_final(const unsigned* __restrict__ umax, const float* __restrict__ fsum,
                             const int* __restrict__ start, float* __restrict__ xpool){
  int g = blockIdx.x; int f = blockIdx.y*256 + threadIdx.x;
  float m = dec_f(umax[g*512 + f]);
  if (!isfinite(m)) m = 0.f;
  int cnt = start[g+1] - start[g];
  xpool[g*1024 + f]       = m;
  xpool[g*1024 + 512 + f] = fsum[g*512 + f] / (float)max(cnt,1);
}

__global__ __launch_bounds__(256) void k_mlp1(const float* __restrict__ xpool, const float* __restrict__ W1,
                       const float* __restrict__ b1, float* __restrict__ hmid){
  __shared__ float part[256];
  int g = blockIdx.x; int c = threadIdx.x & 127; int half = threadIdx.x >> 7;
  float a0=0.f,a1=0.f,a2=0.f,a3=0.f;
  int kb = half*512;
  #pragma unroll 4
  for (int k=0;k<512;k+=4){
    a0 += xpool[g*1024+kb+k+0]*W1[(kb+k+0)*128+c];
    a1 += xpool[g*1024+kb+k+1]*W1[(kb+k+1)*128+c];
    a2 += xpool[g*1024+kb+k+2]*W1[(kb+k+2)*128+c];
    a3 += xpool[g*1024+kb+k+3]*W1[(kb+k+3)*128+c];
  }
  part[threadIdx.x] = (a0+a1)+(a2+a3);
  __syncthreads();
  if (half==0){
    float a = part[c] + part[128+c] + b1[c];
    hmid[g*128+c] = fmaxf(a, 0.f);
  }
}
__global__ void k_mlp2(const float* __restrict__ hmid, const float* __restrict__ W2,
                       const float* __restrict__ b2, float* __restrict__ out){
  int g = threadIdx.x; if (g >= NG) return;
  float a = b2[0];
  for (int k=0;k<128;k++) a += hmid[g*128+k]*W2[k];
  out[g] = a;
}

extern "C" void kernel_launch(void* const* d_in, const int* in_sizes, int n_in,
                              void* d_out, int out_size, void* d_ws, size_t ws_size,
                              hipStream_t stream) {
  const float* x     = (const float*)d_in[0];
  const int*   eidx  = (const int*)d_in[1];
  const int*   eattr = (const int*)d_in[2];
  const float* ew    = (const float*)d_in[3];
  const int*   batch = (const int*)d_in[4];
  const float* irf   = (const float*)d_in[5];
  const float* emb   = (const float*)d_in[6];
  const float* Wl1   = (const float*)d_in[7];
  const float* bl1   = (const float*)d_in[8];
  const float* Wr1   = (const float*)d_in[9];
  const float* br1   = (const float*)d_in[10];
  const float* We1   = (const float*)d_in[11];
  const float* att1  = (const float*)d_in[12];
  const float* bias1 = (const float*)d_in[13];
  const float* Wl2   = (const float*)d_in[14];
  const float* bl2   = (const float*)d_in[15];
  const float* Wr2   = (const float*)d_in[16];
  const float* br2   = (const float*)d_in[17];
  const float* We2   = (const float*)d_in[18];
  const float* att2  = (const float*)d_in[19];
  const float* bias2 = (const float*)d_in[20];
  const float* skipW = (const float*)d_in[21];
  const float* skipb = (const float*)d_in[22];
  const float* W1    = (const float*)d_in[23];
  const float* b1    = (const float*)d_in[24];
  const float* W2    = (const float*)d_in[25];
  const float* b2    = (const float*)d_in[26];

  const int N = in_sizes[4];        // 50000
  const int E = in_sizes[3];        // 800000
  const int* srcp = eidx;
  const int* dstp = eidx + E;

  // ---- workspace carve ----
  char* w = (char*)d_ws;
  size_t off = 0;
  auto alloc = [&](size_t bytes)->void*{
    size_t o = off; off = (off + bytes + 255) & ~(size_t)255; return (void*)(w + o);
  };
  _Float16* efb1h = (_Float16*)alloc((size_t)40*256*2);
  _Float16* efb2h = (_Float16*)alloc((size_t)40*128*2);
  _Float16* W1cat = (_Float16*)alloc((size_t)640*256*2);
  _Float16* W2cat = (_Float16*)alloc((size_t)256*128*2);
  float* bcat1 = (float*)alloc((size_t)640*4);
  float* bcat2 = (float*)alloc((size_t)256*4);
  _Float16* att1h = (_Float16*)alloc((size_t)256*2);
  _Float16* att2h = (_Float16*)alloc((size_t)128*2);
  // zero-init region
  size_t zoff0 = off;
  int*   cnt   = (int*)alloc((size_t)N*4);
  int*   fillc = (int*)alloc((size_t)N*4);
  unsigned* umax = (unsigned*)alloc((size_t)NG*512*4);
  float* fsum  = (float*)alloc((size_t)NG*512*4);
  size_t zlen = off - zoff0;
  int*   rowptr= (int*)alloc((size_t)(N+1)*4);
  int*   incl  = (int*)alloc((size_t)N*4);
  int*   bsum  = (int*)alloc((size_t)64*4);
  int2*  epack = (int2*)alloc((size_t)E*8);
  _Float16* xh = (_Float16*)alloc((size_t)N*256*2);
  _Float16* xl1h = (_Float16*)alloc((size_t)N*256*2);   // compact layer-1 gather table
  _Float16* xrsk = (_Float16*)alloc((size_t)N*384*2);   // xr | xskip, streamed
  _Float16* h1 = (_Float16*)alloc((size_t)N*128*2);
  int*   start = (int*)alloc((size_t)(NG+1)*4);
  float* xpool = (float*)alloc((size_t)NG*1024*4);
  float* hmid  = (float*)alloc((size_t)NG*128*4);
  _Float16* xl2h = xl1h;              // reuse: xl1h dead after attn1
  _Float16* xr2h = xl1h + (size_t)N*128;

  float* outp  = (float*)d_out;        // (64,1)
  float* h2out = (float*)d_out + NG;   // (N,128)

  hipMemsetAsync((char*)d_ws + zoff0, 0, zlen, stream);

  k_setup<<<811, 256, 0, stream>>>(emb, irf, We1, We2, Wl1, Wr1, skipW, Wl2, Wr2,
                                   bl1, br1, skipb, bl2, br2, att1, att2,
                                   efb1h, efb2h, W1cat, W2cat,
                                   bcat1, bcat2, att1h, att2h);
  k_xcvt<<<(N*256/8 + 255)/256, 256, 0, stream>>>(x, xh, N*256/8);

  k_count<<<(E+255)/256, 256, 0, stream>>>(dstp, cnt, E);
  int nb = (N + 1023)/1024;
  k_scan1<<<nb, 1024, 0, stream>>>(cnt, incl, bsum, N);
  k_scan2<<<1, 64, 0, stream>>>(bsum, nb);
  k_scan3<<<(N+255)/256, 256, 0, stream>>>(incl, bsum, rowptr, N);
  k_fill<<<(E+255)/256, 256, 0, stream>>>(srcp, dstp, eattr, ew, rowptr, fillc,
                                          epack, E);

  int gy = (N + 127)/128;
  k_gemm_f16<<<dim3(5, gy), 256, 0, stream>>>(xh, W1cat, bcat1,
                                              xl1h, 256, xrsk, 384, 256, N, 640, 256);

  k_attn1<<<(N+3)/4, 256, 0, stream>>>(xl1h, xrsk, efb1h, att1h, bias1,
                                       rowptr, epack, h1, N);

  k_gemm_f16<<<dim3(2, gy), 256, 0, stream>>>(h1, W2cat, bcat2,
                                              xl2h, 128, xr2h, 128, 128, N, 256, 128);

  k_attn2<<<(N+3)/4, 256, 0, stream>>>(xl2h, xr2h, efb2h, att2h, bias2,
                                       rowptr, epack, h2out, N);

  k_start<<<(N+255)/256, 256, 0, stream>>>(batch, start, N);
  k_pool_part<<<(N+PCHUNK-1)/PCHUNK, 256, 0, stream>>>(xh, h1, h2out, batch, umax, fsum, N);
  k_pool_final<<<dim3(NG,2), 256, 0, stream>>>(umax, fsum, start, xpool);
  k_mlp1<<<NG, 256, 0, stream>>>(xpool, W1, b1, hmid);
  k_mlp2<<<1, 64, 0, stream>>>(hmid, W2, b2, outp);
  (void)n_in; (void)out_size; (void)ws_size;
}

// Round 18
// 343.379 us; speedup vs baseline: 1.1097x; 1.1097x over previous
//
#include <hip/hip_runtime.h>
#include <math.h>

#define EDIM 32
#define NG 64

typedef __attribute__((ext_vector_type(8))) _Float16 f16x8;
typedef __attribute__((ext_vector_type(4))) _Float16 f16x4;
typedef __attribute__((ext_vector_type(2))) _Float16 f16x2;
typedef __attribute__((ext_vector_type(4))) float f32x4;

#if __has_builtin(__builtin_amdgcn_fdot2)
#define USE_FDOT2 1
#else
#define USE_FDOT2 0
#endif

#define THR 4.0f

__device__ inline unsigned enc_f(float f){
  unsigned b = __float_as_uint(f);
  return (b & 0x80000000u) ? ~b : (b | 0x80000000u);
}
__device__ inline float dec_f(unsigned u){
  unsigned b = (u & 0x80000000u) ? (u & 0x7FFFFFFFu) : ~u;
  return __uint_as_float(b);
}
__device__ inline float redux16(float v){
  #pragma unroll
  for (int off=1; off<16; off<<=1) v += __shfl_xor(v, off, 64);
  return v;
}
__device__ inline f16x8 bcast8(_Float16 h){
  f16x8 r;
  #pragma unroll
  for (int z=0;z<8;z++) r[z]=h;
  return r;
}
__device__ inline f16x8 shfl_xor_f16x8(f16x8 v, int off){
  union { f16x8 h; int i[4]; } u;
  u.h = v;
  #pragma unroll
  for (int z=0;z<4;z++) u.i[z] = __shfl_xor(u.i[z], off, 64);
  return u.h;
}
// leaky-relu(m) . att  over 8 f16 channels
__device__ inline float dot_leaky(f16x8 m8, f16x8 a8){
#if __has_builtin(__builtin_elementwise_max)
  f16x8 lm = __builtin_elementwise_max(m8, m8*(_Float16)0.2f);
#else
  f16x8 lm;
  #pragma unroll
  for (int z=0;z<8;z++){ _Float16 v=m8[z]; lm[z] = (v>(_Float16)0)? v : v*(_Float16)0.2f; }
#endif
  float s = 0.f;
#if USE_FDOT2
  #pragma unroll
  for (int z=0;z<4;z++){
    f16x2 u; u[0]=lm[2*z]; u[1]=lm[2*z+1];
    f16x2 w2; w2[0]=a8[2*z]; w2[1]=a8[2*z+1];
    s = __builtin_amdgcn_fdot2(u, w2, s, false);
  }
#else
  #pragma unroll
  for (int z=0;z<8;z++) s += (float)lm[z]*(float)a8[z];
#endif
  return s;
}

// ---------- fused setup: rel tables + weight transposes + bias/att concat ----------
__global__ __launch_bounds__(256) void k_setup(
    const float* __restrict__ emb, const float* __restrict__ irf,
    const float* __restrict__ We1, const float* __restrict__ We2,
    const float* __restrict__ Wl1, const float* __restrict__ Wr1, const float* __restrict__ skipW,
    const float* __restrict__ Wl2, const float* __restrict__ Wr2,
    const float* __restrict__ bl1, const float* __restrict__ br1, const float* __restrict__ skipb,
    const float* __restrict__ bl2, const float* __restrict__ br2,
    const float* __restrict__ att1, const float* __restrict__ att2,
    _Float16* __restrict__ efb1h, _Float16* __restrict__ efb2h,
    _Float16* __restrict__ W1cat, _Float16* __restrict__ W2cat,
    float* __restrict__ bcat1, float* __restrict__ bcat2,
    _Float16* __restrict__ att1h, _Float16* __restrict__ att2h)
{
  int b = blockIdx.x, t = threadIdx.x;
  if (b < 40){
    __shared__ float bb[EDIM];
    int r = b;
    if (t < 32){
      float v = emb[r*EDIM + t];
      float ss = v*v;
      #pragma unroll
      for (int off=16; off>0; off>>=1) ss += __shfl_xor(ss, off, 64);
      float nrm = sqrtf(ss);
      float w = v / fmaxf(nrm, 1e-12f) * irf[r];
      bb[t] = w;
    }
    __syncthreads();
    float a1 = 0.f;
    #pragma unroll
    for (int k=0;k<EDIM;k++) a1 += bb[k]*We1[k*256 + t];
    efb1h[r*256 + t] = (_Float16)a1;
    if (t < 128){
      float a2 = 0.f;
      #pragma unroll
      for (int k=0;k<EDIM;k++) a2 += bb[k]*We2[k*128 + t];
      efb2h[r*128 + t] = (_Float16)a2;
    }
  }
  else if (b < 296){ int idx=(b-40)*256+t;  int k=idx>>8, n2=idx&255; W1cat[n2*256+k]          = (_Float16)Wl1[idx]; }
  else if (b < 552){ int idx=(b-296)*256+t; int k=idx>>8, n2=idx&255; W1cat[65536+n2*256+k]    = (_Float16)Wr1[idx]; }
  else if (b < 680){ int idx=(b-552)*256+t; int k=idx>>7, n2=idx&127; W1cat[131072+n2*256+k]   = (_Float16)skipW[idx]; }
  else if (b < 744){ int idx=(b-680)*256+t; int k=idx>>7, n2=idx&127; W2cat[n2*128+k]          = (_Float16)Wl2[idx]; }
  else if (b < 808){ int idx=(b-744)*256+t; int k=idx>>7, n2=idx&127; W2cat[16384+n2*128+k]    = (_Float16)Wr2[idx]; }
  else if (b == 808){ bcat1[t] = bl1[t]; }
  else if (b == 809){
    bcat1[256+t] = br1[t];
    if (t < 128) bcat1[512+t] = skipb[t];
    att1h[t] = (_Float16)att1[t];
  } else {
    if (t < 128){
      bcat2[t] = bl2[t];
      bcat2[128+t] = br2[t];
      att2h[t] = (_Float16)att2[t];
    }
  }
}

// ---------- x -> fp16 ----------
__global__ void k_xcvt(const float* __restrict__ x, _Float16* __restrict__ xh, int total8){
  int i = blockIdx.x*256 + threadIdx.x;
  if (i < total8){
    float4 v0 = *(const float4*)&x[(size_t)i*8];
    float4 v1 = *(const float4*)&x[(size_t)i*8 + 4];
    f16x8 o;
    o[0]=(_Float16)v0.x; o[1]=(_Float16)v0.y; o[2]=(_Float16)v0.z; o[3]=(_Float16)v0.w;
    o[4]=(_Float16)v1.x; o[5]=(_Float16)v1.y; o[6]=(_Float16)v1.z; o[7]=(_Float16)v1.w;
    *(f16x8*)&xh[(size_t)i*8] = o;
  }
}

// ---------- CSR build ----------
__global__ void k_count(const int* __restrict__ dst, int* __restrict__ cnt, int E){
  int e = blockIdx.x*256 + threadIdx.x;
  if (e < E) atomicAdd(&cnt[dst[e]], 1);
}

__global__ __launch_bounds__(1024) void k_scan1(const int* __restrict__ cnt, int* __restrict__ incl,
                                                int* __restrict__ bsum, int n){
  __shared__ int s[1024];
  int i = blockIdx.x*1024 + threadIdx.x;
  int v = (i<n)? cnt[i] : 0;
  s[threadIdx.x] = v; __syncthreads();
  for (int off=1; off<1024; off<<=1){
    int add = (threadIdx.x>=(unsigned)off)? s[threadIdx.x-off] : 0;
    __syncthreads();
    s[threadIdx.x] += add;
    __syncthreads();
  }
  if (i<n) incl[i] = s[threadIdx.x];
  if (threadIdx.x==1023) bsum[blockIdx.x] = s[1023];
}
__global__ void k_scan2(int* __restrict__ bsum, int nb){
  if (threadIdx.x==0 && blockIdx.x==0){
    int acc=0;
    for (int b=0;b<nb;b++){ int t=bsum[b]; bsum[b]=acc; acc+=t; }
  }
}
__global__ void k_scan3(const int* __restrict__ incl, const int* __restrict__ bsum,
                        int* __restrict__ rowptr, int n){
  int i = blockIdx.x*256 + threadIdx.x;
  if (i<n) rowptr[i+1] = incl[i] + bsum[i>>10];
  if (i==0) rowptr[0] = 0;
}
// scatter ONE packed 8B record per edge: {src | rel<<20, w-bits}
__global__ void k_fill(const int* __restrict__ src, const int* __restrict__ dst,
                       const int* __restrict__ rel, const float* __restrict__ ew,
                       const int* __restrict__ rowptr, int* __restrict__ fill,
                       int2* __restrict__ epack, int E){
  int e = blockIdx.x*256 + threadIdx.x;
  if (e<E){
    int d = dst[e];
    int pos = rowptr[d] + atomicAdd(&fill[d],1);
    int2 rec;
    rec.x = src[e] | (rel[e]<<20);
    rec.y = __float_as_int(ew[e]);
    epack[pos] = rec;
  }
}

// ---------- fp16 MFMA GEMM (double-buffered, XCD-chunk-swizzled): C = A@Bt^T + bias ----------
__global__ __launch_bounds__(256) void k_gemm_f16(
    const _Float16* __restrict__ A, const _Float16* __restrict__ Bt,
    const float* __restrict__ bias, _Float16* __restrict__ C,
    int M, int N, int K)
{
  __shared__ __attribute__((aligned(16))) _Float16 As[2][128][40];
  __shared__ __attribute__((aligned(16))) _Float16 Bs[2][128][40];
  int tid = threadIdx.x;
  int wid = tid>>6, lane = tid&63;
  int wm = (wid>>1)*64, wn = (wid&1)*64;
  // bijective XCD chunk swizzle: HW round-robin (d%8) -> contiguous logical chunks,
  // so the column-blocks sharing A-rows land on one XCD (A L2-resident).
  int nwg = gridDim.x*gridDim.y;
  int d = blockIdx.y*gridDim.x + blockIdx.x;
  int q = nwg>>3, r = nwg&7;
  int xcd = d & 7, idx = d >> 3;
  int logical = xcd*q + min(xcd, r) + idx;
  int bx = logical % gridDim.x, by = logical / gridDim.x;
  int bm = by*128, bn = bx*128;
  int frow = lane&15, fk = (lane>>4)*8;
  int r0c = tid>>2,        s0c = (tid&3)*8;
  int r1c = (tid+256)>>2,  s1c = (tid&3)*8;
  auto loadA = [&](int rr, int s, int k0)->f16x8{
    int gr = bm + rr;
    f16x8 v;
    if (gr < M) v = *(const f16x8*)&A[(size_t)gr*K + k0 + s];
    else { for (int z=0;z<8;z++) v[z]=(_Float16)0.f; }
    return v;
  };
  auto loadB = [&](int rr, int s, int k0)->f16x8{
    return *(const f16x8*)&Bt[(size_t)(bn+rr)*K + k0 + s];
  };
  f32x4 acc[4][4] = {};
  int nt = K >> 5;
  {
    f16x8 a0 = loadA(r0c,s0c,0), a1 = loadA(r1c,s1c,0);
    f16x8 b0 = loadB(r0c,s0c,0), b1 = loadB(r1c,s1c,0);
    *(f16x8*)&As[0][r0c][s0c] = a0;  *(f16x8*)&As[0][r1c][s1c] = a1;
    *(f16x8*)&Bs[0][r0c][s0c] = b0;  *(f16x8*)&Bs[0][r1c][s1c] = b1;
  }
  for (int t=0; t<nt; t++){
    int cur = t&1, nxt = cur^1;
    __syncthreads();
    f16x8 a0,a1,b0,b1;
    bool pf = (t+1 < nt);
    if (pf){
      int k0 = (t+1)<<5;
      a0 = loadA(r0c,s0c,k0); a1 = loadA(r1c,s1c,k0);
      b0 = loadB(r0c,s0c,k0); b1 = loadB(r1c,s1c,k0);
    }
    f16x8 af[4], bfr[4];
    #pragma unroll
    for (int i=0;i<4;i++) af[i]  = *(f16x8*)&As[cur][wm + i*16 + frow][fk];
    #pragma unroll
    for (int j=0;j<4;j++) bfr[j] = *(f16x8*)&Bs[cur][wn + j*16 + frow][fk];
    #pragma unroll
    for (int i=0;i<4;i++)
      #pragma unroll
      for (int j=0;j<4;j++)
        acc[i][j] = __builtin_amdgcn_mfma_f32_16x16x32_f16(af[i], bfr[j], acc[i][j], 0,0,0);
    if (pf){
      *(f16x8*)&As[nxt][r0c][s0c] = a0;  *(f16x8*)&As[nxt][r1c][s1c] = a1;
      *(f16x8*)&Bs[nxt][r0c][s0c] = b0;  *(f16x8*)&Bs[nxt][r1c][s1c] = b1;
    }
  }
  int cl = lane&15, rq = (lane>>4)*4;
  #pragma unroll
  for (int i=0;i<4;i++){
    #pragma unroll
    for (int r4=0;r4<4;r4++){
      int gr = bm + wm + i*16 + rq + r4;
      if (gr < M){
        #pragma unroll
        for (int j=0;j<4;j++){
          int gc = bn + wn + j*16 + cl;
          C[(size_t)gr*N + gc] = (_Float16)(acc[i][j][r4] + bias[gc]);
        }
      }
    }
  }
}

// ---------- fused GATv2 layer 1: H=2; 4 groups = head x edge-parity; 8ch/lane ----------
// efs (self-loop edge feature) accumulated IN the edge loop from the efb rows we gather anyway;
// self-loop softmax term merged at the end (online softmax is order-invariant).
__global__ __launch_bounds__(256) void k_attn1(
  const _Float16* __restrict__ xg,
  const _Float16* __restrict__ efb1h, const _Float16* __restrict__ att1h,
  const float* __restrict__ bias1, const int* __restrict__ rowptr,
  const int2* __restrict__ epack,
  _Float16* __restrict__ h1, int N)
{
  int wv = threadIdx.x>>6, lane = threadIdx.x&63;
  int n = blockIdx.x*4 + wv;
  if (n >= N) return;
  int sub = (lane>>4)&1, t16 = lane&15;
  int ch = (lane>>5)*128 + t16*8;
  f16x8 xrh = *(const f16x8*)&xg[(size_t)n*640 + 256 + ch];
  f16x8 xlh = *(const f16x8*)&xg[(size_t)n*640 + ch];
  f16x8 ath = *(const f16x8*)&att1h[ch];
  f16x8 acc_h = bcast8((_Float16)0.f);
  f16x8 efs_h = bcast8((_Float16)0.f);
  float mx = -1e30f, den = 0.f;

  int beg=rowptr[n], end=rowptr[n+1], p=beg;
  for (; p+4<=end; p+=4){
    int2 pA = epack[p+sub], pB = epack[p+2+sub];
    int iA = (pA.x & 0xFFFFF)*640, rA = (pA.x>>20)<<8; float wA = __int_as_float(pA.y);
    int iB = (pB.x & 0xFFFFF)*640, rB = (pB.x>>20)<<8; float wB = __int_as_float(pB.y);
    f16x8 xvA = *(const f16x8*)&xg[(size_t)iA + ch];
    f16x8 eeA = *(const f16x8*)&efb1h[rA + ch];
    f16x8 xvB = *(const f16x8*)&xg[(size_t)iB + ch];
    f16x8 eeB = *(const f16x8*)&efb1h[rB + ch];
    f16x8 wA8 = bcast8((_Float16)wA), wB8 = bcast8((_Float16)wB);
    f16x8 tA = wA8*eeA, tB = wB8*eeB;
    efs_h = efs_h + tA + tB;
    f16x8 mA = xvA + xrh + tA;
    f16x8 mB = xvB + xrh + tB;
    float sA = dot_leaky(mA, ath);
    float sB = dot_leaky(mB, ath);
    #pragma unroll
    for (int off=1; off<16; off<<=1){
      sA += __shfl_xor(sA, off, 64);
      sB += __shfl_xor(sB, off, 64);
    }
    float gmax = fmaxf(sA, sB);
    if (__all(gmax <= mx + THR)){
      float gA = __expf(sA-mx), gB = __expf(sB-mx);
      den += gA + gB;
      f16x8 gA8 = bcast8((_Float16)gA), gB8 = bcast8((_Float16)gB);
      acc_h = acc_h + xvA*gA8 + xvB*gB8;
    } else {
      float nm = fmaxf(mx, gmax);
      float f = __expf(mx-nm), gA = __expf(sA-nm), gB = __expf(sB-nm);
      den = den*f + gA + gB;
      f16x8 f8 = bcast8((_Float16)f), gA8 = bcast8((_Float16)gA), gB8 = bcast8((_Float16)gB);
      acc_h = acc_h*f8 + xvA*gA8 + xvB*gB8;
      mx = nm;
    }
  }
  for (; p+2<=end; p+=2){
    int2 pE = epack[p+sub];
    int i0 = (pE.x & 0xFFFFF)*640, r0 = (pE.x>>20)<<8; float w0 = __int_as_float(pE.y);
    f16x8 xv = *(const f16x8*)&xg[(size_t)i0 + ch];
    f16x8 ee = *(const f16x8*)&efb1h[r0 + ch];
    f16x8 w8 = bcast8((_Float16)w0);
    f16x8 t0 = w8*ee;
    efs_h = efs_h + t0;
    f16x8 m8 = xv + xrh + t0;
    float sc = redux16(dot_leaky(m8, ath));
    float nm = fmaxf(mx, sc);
    float f = __expf(mx-nm), ge = __expf(sc-nm);
    den = den*f + ge;
    f16x8 f8 = bcast8((_Float16)f), g8 = bcast8((_Float16)ge);
    acc_h = acc_h*f8 + xv*g8;
    mx = nm;
  }
  if (p < end && sub == 0){
    int2 pE = epack[p];
    int i0 = (pE.x & 0xFFFFF)*640, r0 = (pE.x>>20)<<8; float w0 = __int_as_float(pE.y);
    f16x8 xv = *(const f16x8*)&xg[(size_t)i0 + ch];
    f16x8 ee = *(const f16x8*)&efb1h[r0 + ch];
    f16x8 w8 = bcast8((_Float16)w0);
    f16x8 t0 = w8*ee;
    efs_h = efs_h + t0;
    f16x8 m8 = xv + xrh + t0;
    float sc = redux16(dot_leaky(m8, ath));
    float nm = fmaxf(mx, sc);
    float f = __expf(mx-nm), ge = __expf(sc-nm);
    den = den*f + ge;
    f16x8 f8 = bcast8((_Float16)f), g8 = bcast8((_Float16)ge);
    acc_h = acc_h*f8 + xv*g8;
    mx = nm;
  }
  float acc[8];
  #pragma unroll
  for (int z=0;z<8;z++) acc[z] = (float)acc_h[z];
  // merge the two edge-parity groups within each head (acc, den, mx, efs)
  {
    float mo = __shfl_xor(mx, 16, 64);
    float dn = __shfl_xor(den, 16, 64);
    float ao[8];
    #pragma unroll
    for (int z=0;z<8;z++) ao[z] = __shfl_xor(acc[z], 16, 64);
    float mt = fmaxf(mx, mo);
    float fs = __expf(mx-mt), fo = __expf(mo-mt);
    den = den*fs + dn*fo;
    #pragma unroll
    for (int z=0;z<8;z++) acc[z] = acc[z]*fs + ao[z]*fo;
    mx = mt;
    efs_h = efs_h + shfl_xor_f16x8(efs_h, 16);
  }
  // self-loop term (uses fused efs/deg), merged last
  {
    float invdeg = 1.f / (float)max(end-beg, 1);
    f16x8 efh;
    #pragma unroll
    for (int z=0;z<8;z++) efh[z] = (_Float16)((float)efs_h[z]*invdeg);
    f16x8 mself = xlh + xrh + efh;
    float s = redux16(dot_leaky(mself, ath));
    float nm = fmaxf(mx, s);
    float f = __expf(mx-nm), gs = __expf(s-nm);
    den = den*f + gs;
    #pragma unroll
    for (int z=0;z<8;z++) acc[z] = acc[z]*f + gs*(float)xlh[z];
    mx = nm;
  }
  float inv = 1.f/(den + 1e-16f);
  float res[8];
  #pragma unroll
  for (int z=0;z<8;z++){
    float v = acc[z]*inv;
    float o = __shfl_xor(v, 32, 64);
    res[z] = 0.5f*(v + o);
  }
  if (lane < 16){
    f16x8 skh = *(const f16x8*)&xg[(size_t)n*640 + 512 + t16*8];
    f32x4 b0 = *(const f32x4*)&bias1[t16*8];
    f32x4 b1 = *(const f32x4*)&bias1[t16*8 + 4];
    f16x8 o;
    #pragma unroll
    for (int z=0;z<4;z++) o[z]   = (_Float16)fmaxf(res[z]   + b0[z] + (float)skh[z],   0.f);
    #pragma unroll
    for (int z=0;z<4;z++) o[4+z] = (_Float16)fmaxf(res[4+z] + b1[z] + (float)skh[4+z], 0.f);
    *(f16x8*)&h1[(size_t)n*128 + t16*8] = o;
  }
}

// ---------- fused GATv2 layer 2: H=1; 4 edge groups; 8ch/lane; fused efs ----------
__global__ __launch_bounds__(256) void k_attn2(
  const _Float16* __restrict__ xg2,
  const _Float16* __restrict__ efb2h, const _Float16* __restrict__ att2h,
  const float* __restrict__ bias2, const int* __restrict__ rowptr,
  const int2* __restrict__ epack,
  float* __restrict__ h2, int N)
{
  int wv = threadIdx.x>>6, lane = threadIdx.x&63;
  int n = blockIdx.x*4 + wv;
  if (n >= N) return;
  int g = lane>>4, t16 = lane&15;
  int ch = t16*8;
  f16x8 xrh = *(const f16x8*)&xg2[(size_t)n*256 + 128 + ch];
  f16x8 xlh = *(const f16x8*)&xg2[(size_t)n*256 + ch];
  f16x8 ath = *(const f16x8*)&att2h[ch];
  f16x8 acc_h = bcast8((_Float16)0.f);
  f16x8 efs_h = bcast8((_Float16)0.f);
  float mx = -1e30f, den = 0.f;

  int beg=rowptr[n], end=rowptr[n+1], p=beg;
  for (; p+8<=end; p+=8){
    int2 pA = epack[p+g], pB = epack[p+4+g];
    int iA = (pA.x & 0xFFFFF)<<8, rA = (pA.x>>20)<<7; float wA = __int_as_float(pA.y);
    int iB = (pB.x & 0xFFFFF)<<8, rB = (pB.x>>20)<<7; float wB = __int_as_float(pB.y);
    f16x8 xvA = *(const f16x8*)&xg2[(size_t)iA + ch];
    f16x8 eeA = *(const f16x8*)&efb2h[rA + ch];
    f16x8 xvB = *(const f16x8*)&xg2[(size_t)iB + ch];
    f16x8 eeB = *(const f16x8*)&efb2h[rB + ch];
    f16x8 wA8 = bcast8((_Float16)wA), wB8 = bcast8((_Float16)wB);
    f16x8 tA = wA8*eeA, tB = wB8*eeB;
    efs_h = efs_h + tA + tB;
    f16x8 mA = xvA + xrh + tA;
    f16x8 mB = xvB + xrh + tB;
    float sA = dot_leaky(mA, ath);
    float sB = dot_leaky(mB, ath);
    #pragma unroll
    for (int off=1; off<16; off<<=1){
      sA += __shfl_xor(sA, off, 64);
      sB += __shfl_xor(sB, off, 64);
    }
    float gmax = fmaxf(sA, sB);
    if (__all(gmax <= mx + THR)){
      float gA = __expf(sA-mx), gB = __expf(sB-mx);
      den += gA + gB;
      f16x8 gA8 = bcast8((_Float16)gA), gB8 = bcast8((_Float16)gB);
      acc_h = acc_h + xvA*gA8 + xvB*gB8;
    } else {
      float nm = fmaxf(mx, gmax);
      float f = __expf(mx-nm), gA = __expf(sA-nm), gB = __expf(sB-nm);
      den = den*f + gA + gB;
      f16x8 f8 = bcast8((_Float16)f), gA8 = bcast8((_Float16)gA), gB8 = bcast8((_Float16)gB);
      acc_h = acc_h*f8 + xvA*gA8 + xvB*gB8;
      mx = nm;
    }
  }
  for (; p+4<=end; p+=4){
    int2 pE = epack[p+g];
    int i0 = (pE.x & 0xFFFFF)<<8, r0 = (pE.x>>20)<<7; float w0 = __int_as_float(pE.y);
    f16x8 xv = *(const f16x8*)&xg2[(size_t)i0 + ch];
    f16x8 ee = *(const f16x8*)&efb2h[r0 + ch];
    f16x8 w8 = bcast8((_Float16)w0);
    f16x8 t0 = w8*ee;
    efs_h = efs_h + t0;
    f16x8 m8 = xv + xrh + t0;
    float sc = redux16(dot_leaky(m8, ath));
    float nm = fmaxf(mx, sc);
    float f = __expf(mx-nm), ge = __expf(sc-nm);
    den = den*f + ge;
    f16x8 f8 = bcast8((_Float16)f), g8 = bcast8((_Float16)ge);
    acc_h = acc_h*f8 + xv*g8;
    mx = nm;
  }
  int rem = end - p;
  if (g < rem){
    int2 pE = epack[p+g];
    int i0 = (pE.x & 0xFFFFF)<<8, r0 = (pE.x>>20)<<7; float w0 = __int_as_float(pE.y);
    f16x8 xv = *(const f16x8*)&xg2[(size_t)i0 + ch];
    f16x8 ee = *(const f16x8*)&efb2h[r0 + ch];
    f16x8 w8 = bcast8((_Float16)w0);
    f16x8 t0 = w8*ee;
    efs_h = efs_h + t0;
    f16x8 m8 = xv + xrh + t0;
    float sc = redux16(dot_leaky(m8, ath));
    float nm = fmaxf(mx, sc);
    float f = __expf(mx-nm), ge = __expf(sc-nm);
    den = den*f + ge;
    f16x8 f8 = bcast8((_Float16)f), g8 = bcast8((_Float16)ge);
    acc_h = acc_h*f8 + xv*g8;
    mx = nm;
  }
  float acc[8];
  #pragma unroll
  for (int z=0;z<8;z++) acc[z] = (float)acc_h[z];
  // butterfly-merge the 4 group states (acc, den, mx, efs)
  #pragma unroll
  for (int off=16; off<=32; off<<=1){
    float mo = __shfl_xor(mx, off, 64);
    float dn = __shfl_xor(den, off, 64);
    float ao[8];
    #pragma unroll
    for (int z=0;z<8;z++) ao[z] = __shfl_xor(acc[z], off, 64);
    float mt = fmaxf(mx, mo);
    float fs = __expf(mx-mt), fo = __expf(mo-mt);
    den = den*fs + dn*fo;
    #pragma unroll
    for (int z=0;z<8;z++) acc[z] = acc[z]*fs + ao[z]*fo;
    mx = mt;
    efs_h = efs_h + shfl_xor_f16x8(efs_h, off);
  }
  // self-loop term
  {
    float invdeg = 1.f / (float)max(end-beg, 1);
    f16x8 efh;
    #pragma unroll
    for (int z=0;z<8;z++) efh[z] = (_Float16)((float)efs_h[z]*invdeg);
    f16x8 mself = xlh + xrh + efh;
    float s = redux16(dot_leaky(mself, ath));
    float nm = fmaxf(mx, s);
    float f = __expf(mx-nm), gs = __expf(s-nm);
    den = den*f + gs;
    #pragma unroll
    for (int z=0;z<8;z++) acc[z] = acc[z]*f + gs*(float)xlh[z];
    mx = nm;
  }
  float inv = 1.f/(den + 1e-16f);
  if (g == 0){
    f32x4 b0 = *(const f32x4*)&bias2[ch];
    f32x4 b1 = *(const f32x4*)&bias2[ch+4];
    f32x4 o0, o1;
    #pragma unroll
    for (int z=0;z<4;z++){ o0[z] = fmaxf(acc[z]*inv   + b0[z], 0.f);
                           o1[z] = fmaxf(acc[4+z]*inv + b1[z], 0.f); }
    *(f32x4*)&h2[(size_t)n*128 + ch]     = o0;
    *(f32x4*)&h2[(size_t)n*128 + ch + 4] = o1;
  }
}

// ---------- graph boundaries ----------
__global__ void k_start(const int* __restrict__ batch, int* __restrict__ start, int N){
  int i = blockIdx.x*256 + threadIdx.x;
  if (i >= N) return;
  int b = batch[i];
  int pb = (i==0)? -1 : batch[i-1];
  for (int g=pb+1; g<=b; g++) start[g] = i;
  if (i == N-1){ for (int g=b+1; g<=NG; g++) start[g] = N; }
}

// ---------- pooling stage A ----------
#define PCHUNK 32
__global__ __launch_bounds__(256) void k_pool_part(const float* __restrict__ x, const _Float16* __restrict__ h1,
                       const float* __restrict__ h2, const int* __restrict__ batch,
                       unsigned* __restrict__ umax, float* __restrict__ fsum, int N){
  int c0 = blockIdx.x * PCHUNK;
  int c1 = min(c0 + PCHUNK, N);
  if (c0 >= N) return;
  int t = threadIdx.x;
  float mx0 = -INFINITY, sm0 = 0.f, mx1 = -INFINITY, sm1 = 0.f;
  int bcur = batch[c0];
  for (int i=c0;i<c1;i++){
    int b = batch[i];
    if (b != bcur){
      atomicMax(&umax[bcur*512 + t], enc_f(mx0));
      atomicAdd(&fsum[bcur*512 + t], sm0);
      atomicMax(&umax[bcur*512 + 256 + t], enc_f(mx1));
      atomicAdd(&fsum[bcur*512 + 256 + t], sm1);
      mx0 = mx1 = -INFINITY; sm0 = sm1 = 0.f; bcur = b;
    }
    float v0 = x[(size_t)i*256 + t];
    float v1 = (t<128) ? (float)h1[(size_t)i*128 + t] : h2[(size_t)i*128 + (t-128)];
    mx0 = fmaxf(mx0, v0); sm0 += v0;
    mx1 = fmaxf(mx1, v1); sm1 += v1;
  }
  atomicMax(&umax[bcur*512 + t], enc_f(mx0));
  atomicAdd(&fsum[bcur*512 + t], sm0);
  atomicMax(&umax[bcur*512 + 256 + t], enc_f(mx1));
  atomicAdd(&fsum[bcur*512 + 256 + t], sm1);
}

// ---------- pooling stage B ----------
__global__ void k_pool_final(const unsigned* __restrict__ umax, const float* __restrict__ fsum,
                             const int* __restrict__ start, float* __restrict__ xpool){
  int g = blockIdx.x; int f = blockIdx.y*256 + threadIdx.x;
  float m = dec_f(umax[g*512 + f]);
  if (!isfinite(m)) m = 0.f;
  int cnt = start[g+1] - start[g];
  xpool[g*1024 + f]       = m;
  xpool[g*1024 + 512 + f] = fsum[g*512 + f] / (float)max(cnt,1);
}

__global__ __launch_bounds__(256) void k_mlp1(const float* __restrict__ xpool, const float* __restrict__ W1,
                       const float* __restrict__ b1, float* __restrict__ hmid){
  __shared__ float part[256];
  int g = blockIdx.x; int c = threadIdx.x & 127; int half = threadIdx.x >> 7;
  float a0=0.f,a1=0.f,a2=0.f,a3=0.f;
  int kb = half*512;
  #pragma unroll 4
  for (int k=0;k<512;k+=4){
    a0 += xpool[g*1024+kb+k+0]*W1[(kb+k+0)*128+c];
    a1 += xpool[g*1024+kb+k+1]*W1[(kb+k+1)*128+c];
    a2 += xpool[g*1024+kb+k+2]*W1[(kb+k+2)*128+c];
    a3 += xpool[g*1024+kb+k+3]*W1[(kb+k+3)*128+c];
  }
  part[threadIdx.x] = (a0+a1)+(a2+a3);
  __syncthreads();
  if (half==0){
    float a = part[c] + part[128+c] + b1[c];
    hmid[g*128+c] = fmaxf(a, 0.f);
  }
}
__global__ void k_mlp2(const float* __restrict__ hmid, const float* __restrict__ W2,
                       const float* __restrict__ b2, float* __restrict__ out){
  int g = threadIdx.x; if (g >= NG) return;
  float a = b2[0];
  for (int k=0;k<128;k++) a += hmid[g*128+k]*W2[k];
  out[g] = a;
}

extern "C" void kernel_launch(void* const* d_in, const int* in_sizes, int n_in,
                              void* d_out, int out_size, void* d_ws, size_t ws_size,
                              hipStream_t stream) {
  const float* x     = (const float*)d_in[0];
  const int*   eidx  = (const int*)d_in[1];
  const int*   eattr = (const int*)d_in[2];
  const float* ew    = (const float*)d_in[3];
  const int*   batch = (const int*)d_in[4];
  const float* irf   = (const float*)d_in[5];
  const float* emb   = (const float*)d_in[6];
  const float* Wl1   = (const float*)d_in[7];
  const float* bl1   = (const float*)d_in[8];
  const float* Wr1   = (const float*)d_in[9];
  const float* br1   = (const float*)d_in[10];
  const float* We1   = (const float*)d_in[11];
  const float* att1  = (const float*)d_in[12];
  const float* bias1 = (const float*)d_in[13];
  const float* Wl2   = (const float*)d_in[14];
  const float* bl2   = (const float*)d_in[15];
  const float* Wr2   = (const float*)d_in[16];
  const float* br2   = (const float*)d_in[17];
  const float* We2   = (const float*)d_in[18];
  const float* att2  = (const float*)d_in[19];
  const float* bias2 = (const float*)d_in[20];
  const float* skipW = (const float*)d_in[21];
  const float* skipb = (const float*)d_in[22];
  const float* W1    = (const float*)d_in[23];
  const float* b1    = (const float*)d_in[24];
  const float* W2    = (const float*)d_in[25];
  const float* b2    = (const float*)d_in[26];

  const int N = in_sizes[4];        // 50000
  const int E = in_sizes[3];        // 800000
  const int* srcp = eidx;
  const int* dstp = eidx + E;

  // ---- workspace carve ----
  char* w = (char*)d_ws;
  size_t off = 0;
  auto alloc = [&](size_t bytes)->void*{
    size_t o = off; off = (off + bytes + 255) & ~(size_t)255; return (void*)(w + o);
  };
  _Float16* efb1h = (_Float16*)alloc((size_t)40*256*2);
  _Float16* efb2h = (_Float16*)alloc((size_t)40*128*2);
  _Float16* W1cat = (_Float16*)alloc((size_t)640*256*2);
  _Float16* W2cat = (_Float16*)alloc((size_t)256*128*2);
  float* bcat1 = (float*)alloc((size_t)640*4);
  float* bcat2 = (float*)alloc((size_t)256*4);
  _Float16* att1h = (_Float16*)alloc((size_t)256*2);
  _Float16* att2h = (_Float16*)alloc((size_t)128*2);
  // zero-init region
  size_t zoff0 = off;
  int*   cnt   = (int*)alloc((size_t)N*4);
  int*   fillc = (int*)alloc((size_t)N*4);
  unsigned* umax = (unsigned*)alloc((size_t)NG*512*4);
  float* fsum  = (float*)alloc((size_t)NG*512*4);
  size_t zlen = off - zoff0;
  int*   rowptr= (int*)alloc((size_t)(N+1)*4);
  int*   incl  = (int*)alloc((size_t)N*4);
  int*   bsum  = (int*)alloc((size_t)64*4);
  int2*  epack = (int2*)alloc((size_t)E*8);
  _Float16* xh = (_Float16*)alloc((size_t)N*256*2);
  _Float16* xg = (_Float16*)alloc((size_t)N*640*2);
  _Float16* h1 = (_Float16*)alloc((size_t)N*128*2);
  int*   start = (int*)alloc((size_t)(NG+1)*4);
  float* xpool = (float*)alloc((size_t)NG*1024*4);
  float* hmid  = (float*)alloc((size_t)NG*128*4);
  _Float16* xg2 = xg;       // reuse: xg dead after attn1

  float* outp  = (float*)d_out;        // (64,1)
  float* h2out = (float*)d_out + NG;   // (N,128)

  hipMemsetAsync((char*)d_ws + zoff0, 0, zlen, stream);

  k_setup<<<811, 256, 0, stream>>>(emb, irf, We1, We2, Wl1, Wr1, skipW, Wl2, Wr2,
                                   bl1, br1, skipb, bl2, br2, att1, att2,
                                   efb1h, efb2h, W1cat, W2cat,
                                   bcat1, bcat2, att1h, att2h);
  k_xcvt<<<(N*256/8 + 255)/256, 256, 0, stream>>>(x, xh, N*256/8);

  k_count<<<(E+255)/256, 256, 0, stream>>>(dstp, cnt, E);
  int nb = (N + 1023)/1024;
  k_scan1<<<nb, 1024, 0, stream>>>(cnt, incl, bsum, N);
  k_scan2<<<1, 64, 0, stream>>>(bsum, nb);
  k_scan3<<<(N+255)/256, 256, 0, stream>>>(incl, bsum, rowptr, N);
  k_fill<<<(E+255)/256, 256, 0, stream>>>(srcp, dstp, eattr, ew, rowptr, fillc,
                                          epack, E);

  int gy = (N + 127)/128;
  k_gemm_f16<<<dim3(5, gy), 256, 0, stream>>>(xh, W1cat, bcat1, xg, N, 640, 256);

  k_attn1<<<(N+3)/4, 256, 0, stream>>>(xg, efb1h, att1h, bias1,
                                       rowptr, epack, h1, N);

  k_gemm_f16<<<dim3(2, gy), 256, 0, stream>>>(h1, W2cat, bcat2, xg2, N, 256, 128);

  k_attn2<<<(N+3)/4, 256, 0, stream>>>(xg2, efb2h, att2h, bias2,
                                       rowptr, epack, h2out, N);

  k_start<<<(N+255)/256, 256, 0, stream>>>(batch, start, N);
  k_pool_part<<<(N+PCHUNK-1)/PCHUNK, 256, 0, stream>>>(x, h1, h2out, batch, umax, fsum, N);
  k_pool_final<<<dim3(NG,2), 256, 0, stream>>>(umax, fsum, start, xpool);
  k_mlp1<<<NG, 256, 0, stream>>>(xpool, W1, b1, hmid);
  k_mlp2<<<1, 64, 0, stream>>>(hmid, W2, b2, outp);
  (void)n_in; (void)out_size; (void)ws_size;
}